// Round 4
// baseline (300.334 us; speedup 1.0000x reference)
//
#include <hip/hip_runtime.h>
#include <hip/hip_fp16.h>

#define N_NODES 100000
#define N_EDGES 1600000
#define DCAP 64             // slots per node; Poisson(16), P(deg>64) ~ 1e-21
#define SCAT_BLOCKS 782     // ceil((E/4)/512) int4-threads
#define P1_BLOCKS 391       // 391*256 = 100096 >= N+1 nodes
#define NBF_G 1563          // gather grid: 64 nodes/block, covers N + sentinel

// deg[] is COUNTS (0-initialized via hipMemsetAsync). The scatter atomic
// returns each edge's rank, so deg doubles as rank-cursor and final degree.
// CSR is implicit: row n lives at srcByDst[n*DCAP .. n*DCAP+deg[n]).

// ---------------- pass 1: direct scatter into fixed-slot CSR ----------------
// No LDS, no histogram, no scan, no capacity-padded intermediate.
__global__ __launch_bounds__(512) void k_scat(const int* __restrict__ src,
                                              const int* __restrict__ dst,
                                              int* __restrict__ deg,
                                              int* __restrict__ srcByDst) {
    int g = blockIdx.x * 512 + threadIdx.x;
    if (g >= N_EDGES / 4) return;
    int4 s4 = reinterpret_cast<const int4*>(src)[g];
    int4 d4 = reinterpret_cast<const int4*>(dst)[g];
    int ds[4] = {d4.x, d4.y, d4.z, d4.w};
    int ss[4] = {s4.x, s4.y, s4.z, s4.w};
#pragma unroll
    for (int j = 0; j < 4; ++j) {
        int r = atomicAdd(&deg[ds[j]], 1);
        if (r < DCAP)   // statistically impossible overflow guard
            srcByDst[(size_t)ds[j] * DCAP + r] = ss[j];
    }
}

// ---------------- pass 2: p1 = dinv * (x @ W1), pure streaming ----------------
// Needs completed deg (for dinv). Also writes the sentinel zero row p1[N].
__global__ __launch_bounds__(512) void k_p1(const int* __restrict__ deg,
                                            const float* __restrict__ x,
                                            const float* __restrict__ W1,
                                            __half* __restrict__ p1) {
    __shared__ float sW[1024];
    int t = threadIdx.x;
    for (int i = t; i < 1024; i += 512) sW[i] = W1[i];
    __syncthreads();
    int lane = t & 31;
    int b = blockIdx.x;
    for (int r = (t >> 5); r < 256; r += 16) {
        int nd = b * 256 + r;
        if (nd > N_NODES) break;
        if (nd == N_NODES) {                      // sentinel zero row
            p1[nd * 32 + lane] = __float2half(0.f);
            continue;
        }
        float xv = x[nd * 32 + lane];
        float a = 0.f;
#pragma unroll
        for (int k = 0; k < 32; ++k) {
            float xk = __shfl(xv, k, 32);
            a += xk * sW[k * 32 + lane];
        }
        float di = rsqrtf((float)(deg[nd] + 1));  // +1 = self loop
        p1[nd * 32 + lane] = __float2half(di * a);
    }
}

// ---------------- 4-lane gather: lane owns channels 8l..8l+7, 16B loads --------
// One VMEM instr covers 16 edges/wave. Tail edges load the sentinel zero row
// (index N_NODES) instead of branching. fp16 8-term tree partials -> fp32 flush.
__device__ __forceinline__ __half2 h2of(const float4& v, int c) {
    return reinterpret_cast<const __half2*>(&v)[c];
}

__device__ __forceinline__ void gatherRow4(const int* __restrict__ srcByDst,
                                           const float4* __restrict__ P,
                                           int beg, int end, int l,
                                           float* __restrict__ acc /*[8]*/) {
    for (int base = beg; base < end; base += 8) {
        int i0 = base + l, i1 = base + 4 + l;
        int sA = (i0 < end) ? srcByDst[i0] : N_NODES;
        int sB = (i1 < end) ? srcByDst[i1] : N_NODES;
        float4 v0 = P[__shfl(sA, 0, 4) * 4 + l];
        float4 v1 = P[__shfl(sA, 1, 4) * 4 + l];
        float4 v2 = P[__shfl(sA, 2, 4) * 4 + l];
        float4 v3 = P[__shfl(sA, 3, 4) * 4 + l];
        float4 v4 = P[__shfl(sB, 0, 4) * 4 + l];
        float4 v5 = P[__shfl(sB, 1, 4) * 4 + l];
        float4 v6 = P[__shfl(sB, 2, 4) * 4 + l];
        float4 v7 = P[__shfl(sB, 3, 4) * 4 + l];
#pragma unroll
        for (int c = 0; c < 4; ++c) {
            __half2 s01 = __hadd2(h2of(v0, c), h2of(v1, c));
            __half2 s23 = __hadd2(h2of(v2, c), h2of(v3, c));
            __half2 s45 = __hadd2(h2of(v4, c), h2of(v5, c));
            __half2 s67 = __hadd2(h2of(v6, c), h2of(v7, c));
            __half2 sum = __hadd2(__hadd2(s01, s23), __hadd2(s45, s67));
            float2 f = __half22float2(sum);
            acc[2 * c]     += f.x;
            acc[2 * c + 1] += f.y;
        }
    }
}

// ---------------- gather layer 1 + relu + layer-2 matmul (4 lanes/node) --------
__global__ __launch_bounds__(256) void k_gx2(const int* __restrict__ deg,
                                             const int* __restrict__ srcByDst,
                                             const __half* __restrict__ p1,
                                             const float* __restrict__ b1,
                                             const float* __restrict__ Wmu,
                                             const float* __restrict__ Wlv,
                                             __half* __restrict__ p2) {
    __shared__ float sW[1024];       // [k][oc], oc: 0-15 mu, 16-31 lv
    __shared__ float sB[32];
    int t = threadIdx.x;
    for (int i = t; i < 1024; i += 256) {
        int k = i >> 5, oc = i & 31;
        sW[i] = (oc < 16) ? Wmu[k * 16 + oc] : Wlv[k * 16 + (oc - 16)];
    }
    if (t < 32) sB[t] = b1[t];
    __syncthreads();
    int l = t & 3;
    int node = blockIdx.x * 64 + (t >> 2);   // 1563*64 covers N + sentinel
    if (node > N_NODES) return;
    const float4* P = (const float4*)p1;
    if (node == N_NODES) {                   // sentinel zero row of p2
        ((float4*)p2)[node * 4 + l] = make_float4(0.f, 0.f, 0.f, 0.f);
        return;
    }
    int dgw = deg[node];
    int dg = (dgw < DCAP) ? dgw : DCAP;
    int beg = node * DCAP;
    float di = rsqrtf((float)(dgw + 1));
    float acc[8] = {0.f, 0.f, 0.f, 0.f, 0.f, 0.f, 0.f, 0.f};
    gatherRow4(srcByDst, P, beg, beg + dg, l, acc);
    float4 ps = P[node * 4 + l];             // self loop analytic
    float h[8];
#pragma unroll
    for (int c = 0; c < 4; ++c) {
        float2 f = __half22float2(h2of(ps, c));
        h[2 * c]     = fmaxf(di * (acc[2 * c]     + f.x) + sB[8 * l + 2 * c],     0.f);
        h[2 * c + 1] = fmaxf(di * (acc[2 * c + 1] + f.y) + sB[8 * l + 2 * c + 1], 0.f);
    }
    float o[8] = {0.f, 0.f, 0.f, 0.f, 0.f, 0.f, 0.f, 0.f};
    const float4* W4 = (const float4*)sW;
#pragma unroll
    for (int m = 0; m < 4; ++m) {
#pragma unroll
        for (int j = 0; j < 8; ++j) {
            float hk = __shfl(h[j], m, 4);   // channel k = 8m+j
            int k = 8 * m + j;
            float4 wa = W4[k * 8 + 2 * l];
            float4 wb = W4[k * 8 + 2 * l + 1];
            o[0] += hk * wa.x; o[1] += hk * wa.y; o[2] += hk * wa.z; o[3] += hk * wa.w;
            o[4] += hk * wb.x; o[5] += hk * wb.y; o[6] += hk * wb.z; o[7] += hk * wb.w;
        }
    }
    __half2 r0 = __floats2half2_rn(di * o[0], di * o[1]);
    __half2 r1 = __floats2half2_rn(di * o[2], di * o[3]);
    __half2 r2 = __floats2half2_rn(di * o[4], di * o[5]);
    __half2 r3 = __floats2half2_rn(di * o[6], di * o[7]);
    float4 st;
    st.x = *reinterpret_cast<float*>(&r0);
    st.y = *reinterpret_cast<float*>(&r1);
    st.z = *reinterpret_cast<float*>(&r2);
    st.w = *reinterpret_cast<float*>(&r3);
    ((float4*)p2)[node * 4 + l] = st;
}

// ---------------- gather layer 2 + mu/logvar epilogue (4 lanes/node) ----------
__global__ __launch_bounds__(256) void k_gfin(const int* __restrict__ deg,
                                              const int* __restrict__ srcByDst,
                                              const __half* __restrict__ p2,
                                              const float* __restrict__ bmu,
                                              const float* __restrict__ blv,
                                              float* __restrict__ out) {
    __shared__ float sB[32];
    int t = threadIdx.x;
    if (t < 32) sB[t] = (t < 16) ? bmu[t] : blv[t - 16];
    __syncthreads();
    int l = t & 3;
    int node = blockIdx.x * 64 + (t >> 2);
    if (node >= N_NODES) return;
    const float4* P = (const float4*)p2;
    int dgw = deg[node];
    int dg = (dgw < DCAP) ? dgw : DCAP;
    int beg = node * DCAP;
    float di = rsqrtf((float)(dgw + 1));
    float acc[8] = {0.f, 0.f, 0.f, 0.f, 0.f, 0.f, 0.f, 0.f};
    gatherRow4(srcByDst, P, beg, beg + dg, l, acc);
    float4 ps = P[node * 4 + l];
    float v[8];
#pragma unroll
    for (int c = 0; c < 4; ++c) {
        float2 f = __half22float2(h2of(ps, c));
        v[2 * c]     = di * (acc[2 * c]     + f.x) + sB[8 * l + 2 * c];
        v[2 * c + 1] = di * (acc[2 * c + 1] + f.y) + sB[8 * l + 2 * c + 1];
    }
    float4 o0 = make_float4(v[0], v[1], v[2], v[3]);
    float4 o1 = make_float4(v[4], v[5], v[6], v[7]);
    float4* dst4 = (l < 2) ? (float4*)out
                           : (float4*)(out + (size_t)N_NODES * 16);
    int b4 = node * 4 + (l & 1) * 2;
    dst4[b4]     = o0;
    dst4[b4 + 1] = o1;
}

extern "C" void kernel_launch(void* const* d_in, const int* in_sizes, int n_in,
                              void* d_out, int out_size, void* d_ws, size_t ws_size,
                              hipStream_t stream) {
    const float* x   = (const float*)d_in[0];
    const int*   ei  = (const int*)d_in[1];
    const float* W1  = (const float*)d_in[2];
    const float* b1  = (const float*)d_in[3];
    const float* Wmu = (const float*)d_in[4];
    const float* bmu = (const float*)d_in[5];
    const float* Wlv = (const float*)d_in[6];
    const float* blv = (const float*)d_in[7];
    float* out = (float*)d_out;

    const int* src = ei;            // edge_index[0]
    const int* dst = ei + N_EDGES;  // edge_index[1]

    // workspace (4B units), 256B-aligned big buffers for float4 access:
    //  deg[N+1]  (COUNTS, zeroed by memset below; doubles as rank cursor)
    //  | srcByDst[N*64]  (implicit CSR, fixed 64 slots/node)
    //  | p1[(N+1)*32 halves] | p2[(N+1)*32 halves]
    size_t off = 0;
    int* deg = (int*)d_ws;                              off += N_NODES + 1;
    off = (off + 63) & ~(size_t)63;                     // 256B align
    int* srcByDst = (int*)d_ws + off;                   off += (size_t)N_NODES * DCAP;
    off = (off + 63) & ~(size_t)63;
    __half* p1h = (__half*)((int*)d_ws + off);          off += (size_t)(N_NODES + 1) * 16;
    off = (off + 63) & ~(size_t)63;
    __half* p2h = (__half*)((int*)d_ws + off);

    hipMemsetAsync(d_ws, 0, (size_t)(N_NODES + 1) * sizeof(int), stream);
    k_scat<<<SCAT_BLOCKS, 512, 0, stream>>>(src, dst, deg, srcByDst);
    k_p1  <<<P1_BLOCKS, 512, 0, stream>>>(deg, x, W1, p1h);
    k_gx2 <<<NBF_G, 256, 0, stream>>>(deg, srcByDst, p1h, b1, Wmu, Wlv, p2h);
    k_gfin<<<NBF_G, 256, 0, stream>>>(deg, srcByDst, p2h, bmu, blv, out);
}

// Round 5
// 234.964 us; speedup vs baseline: 1.2782x; 1.2782x over previous
//
#include <hip/hip_runtime.h>
#include <hip/hip_fp16.h>

#define N_NODES 100000
#define N_EDGES 1600000
#define DCAP 64             // slots per node; Poisson(16), P(deg>64) ~ 1e-21
#define NPART 12500         // nodes per XCD class (8 * 12500 = 100000)
#define SCAT_BPC 128        // blocks per class
#define SCAT_CHUNK 3125     // int4-groups per class-block (128*3125 = E/4)
#define P1_BLOCKS 391       // 391*256 = 100096 >= N+1 nodes
#define NBF_G 1563          // gather grid: 64 nodes/block, covers N + sentinel

// deg[] is COUNTS (0-initialized via hipMemsetAsync). The scatter atomic
// returns each edge's rank, so deg doubles as rank-cursor and final degree.
// CSR is implicit: row n lives at srcByDst[n*DCAP .. n*DCAP+deg[n]).

// ---------------- pass 1: XCD-affine scatter into fixed-slot CSR ----------------
// Class c = blockIdx&7 maps to XCD c (round-robin dispatch heuristic). Each
// class scans ALL edges but scatters only dst in [c*NPART, (c+1)*NPART): the
// 3.2MB write window fits that XCD's private L2, so each 64B line is written
// back once instead of ~4 partial-line RMWs from random XCDs. The 8x edge-list
// re-read is L2-absorbed (all classes stream in lockstep).
__global__ __launch_bounds__(512) void k_scat(const int* __restrict__ src,
                                              const int* __restrict__ dst,
                                              int* __restrict__ deg,
                                              int* __restrict__ srcByDst) {
    int cls  = blockIdx.x & 7;
    int widx = blockIdx.x >> 3;
    int lo = cls * NPART, hi = lo + NPART;
    int base = widx * SCAT_CHUNK;
    for (int i = threadIdx.x; i < SCAT_CHUNK; i += 512) {
        int g = base + i;
        int4 s4 = reinterpret_cast<const int4*>(src)[g];
        int4 d4 = reinterpret_cast<const int4*>(dst)[g];
        int ds[4] = {d4.x, d4.y, d4.z, d4.w};
        int ss[4] = {s4.x, s4.y, s4.z, s4.w};
#pragma unroll
        for (int j = 0; j < 4; ++j) {
            if (ds[j] >= lo && ds[j] < hi) {
                int r = atomicAdd(&deg[ds[j]], 1);
                if (r < DCAP)   // statistically impossible overflow guard
                    srcByDst[(size_t)ds[j] * DCAP + r] = ss[j];
            }
        }
    }
}

// ---------------- pass 2: p1 = dinv * (x @ W1), pure streaming ----------------
// Needs completed deg (for dinv). Also writes the sentinel zero row p1[N].
__global__ __launch_bounds__(512) void k_p1(const int* __restrict__ deg,
                                            const float* __restrict__ x,
                                            const float* __restrict__ W1,
                                            __half* __restrict__ p1) {
    __shared__ float sW[1024];
    int t = threadIdx.x;
    for (int i = t; i < 1024; i += 512) sW[i] = W1[i];
    __syncthreads();
    int lane = t & 31;
    int b = blockIdx.x;
    for (int r = (t >> 5); r < 256; r += 16) {
        int nd = b * 256 + r;
        if (nd > N_NODES) break;
        if (nd == N_NODES) {                      // sentinel zero row
            p1[nd * 32 + lane] = __float2half(0.f);
            continue;
        }
        float xv = x[nd * 32 + lane];
        float a = 0.f;
#pragma unroll
        for (int k = 0; k < 32; ++k) {
            float xk = __shfl(xv, k, 32);
            a += xk * sW[k * 32 + lane];
        }
        float di = rsqrtf((float)(deg[nd] + 1));  // +1 = self loop
        p1[nd * 32 + lane] = __float2half(di * a);
    }
}

// ---------------- 4-lane gather: lane owns channels 8l..8l+7, 16B loads --------
// One VMEM instr covers 16 edges/wave. Tail edges load the sentinel zero row
// (index N_NODES) instead of branching. fp16 8-term tree partials -> fp32 flush.
__device__ __forceinline__ __half2 h2of(const float4& v, int c) {
    return reinterpret_cast<const __half2*>(&v)[c];
}

__device__ __forceinline__ void gatherRow4(const int* __restrict__ srcByDst,
                                           const float4* __restrict__ P,
                                           int beg, int end, int l,
                                           float* __restrict__ acc /*[8]*/) {
    for (int base = beg; base < end; base += 8) {
        int i0 = base + l, i1 = base + 4 + l;
        int sA = (i0 < end) ? srcByDst[i0] : N_NODES;
        int sB = (i1 < end) ? srcByDst[i1] : N_NODES;
        float4 v0 = P[__shfl(sA, 0, 4) * 4 + l];
        float4 v1 = P[__shfl(sA, 1, 4) * 4 + l];
        float4 v2 = P[__shfl(sA, 2, 4) * 4 + l];
        float4 v3 = P[__shfl(sA, 3, 4) * 4 + l];
        float4 v4 = P[__shfl(sB, 0, 4) * 4 + l];
        float4 v5 = P[__shfl(sB, 1, 4) * 4 + l];
        float4 v6 = P[__shfl(sB, 2, 4) * 4 + l];
        float4 v7 = P[__shfl(sB, 3, 4) * 4 + l];
#pragma unroll
        for (int c = 0; c < 4; ++c) {
            __half2 s01 = __hadd2(h2of(v0, c), h2of(v1, c));
            __half2 s23 = __hadd2(h2of(v2, c), h2of(v3, c));
            __half2 s45 = __hadd2(h2of(v4, c), h2of(v5, c));
            __half2 s67 = __hadd2(h2of(v6, c), h2of(v7, c));
            __half2 sum = __hadd2(__hadd2(s01, s23), __hadd2(s45, s67));
            float2 f = __half22float2(sum);
            acc[2 * c]     += f.x;
            acc[2 * c + 1] += f.y;
        }
    }
}

// ---------------- gather layer 1 + relu + layer-2 matmul (4 lanes/node) --------
__global__ __launch_bounds__(256) void k_gx2(const int* __restrict__ deg,
                                             const int* __restrict__ srcByDst,
                                             const __half* __restrict__ p1,
                                             const float* __restrict__ b1,
                                             const float* __restrict__ Wmu,
                                             const float* __restrict__ Wlv,
                                             __half* __restrict__ p2) {
    __shared__ float sW[1024];       // [k][oc], oc: 0-15 mu, 16-31 lv
    __shared__ float sB[32];
    int t = threadIdx.x;
    for (int i = t; i < 1024; i += 256) {
        int k = i >> 5, oc = i & 31;
        sW[i] = (oc < 16) ? Wmu[k * 16 + oc] : Wlv[k * 16 + (oc - 16)];
    }
    if (t < 32) sB[t] = b1[t];
    __syncthreads();
    int l = t & 3;
    int node = blockIdx.x * 64 + (t >> 2);   // 1563*64 covers N + sentinel
    if (node > N_NODES) return;
    const float4* P = (const float4*)p1;
    if (node == N_NODES) {                   // sentinel zero row of p2
        ((float4*)p2)[node * 4 + l] = make_float4(0.f, 0.f, 0.f, 0.f);
        return;
    }
    int dgw = deg[node];
    int dg = (dgw < DCAP) ? dgw : DCAP;
    int beg = node * DCAP;
    float di = rsqrtf((float)(dgw + 1));
    float acc[8] = {0.f, 0.f, 0.f, 0.f, 0.f, 0.f, 0.f, 0.f};
    gatherRow4(srcByDst, P, beg, beg + dg, l, acc);
    float4 ps = P[node * 4 + l];             // self loop analytic
    float h[8];
#pragma unroll
    for (int c = 0; c < 4; ++c) {
        float2 f = __half22float2(h2of(ps, c));
        h[2 * c]     = fmaxf(di * (acc[2 * c]     + f.x) + sB[8 * l + 2 * c],     0.f);
        h[2 * c + 1] = fmaxf(di * (acc[2 * c + 1] + f.y) + sB[8 * l + 2 * c + 1], 0.f);
    }
    float o[8] = {0.f, 0.f, 0.f, 0.f, 0.f, 0.f, 0.f, 0.f};
    const float4* W4 = (const float4*)sW;
#pragma unroll
    for (int m = 0; m < 4; ++m) {
#pragma unroll
        for (int j = 0; j < 8; ++j) {
            float hk = __shfl(h[j], m, 4);   // channel k = 8m+j
            int k = 8 * m + j;
            float4 wa = W4[k * 8 + 2 * l];
            float4 wb = W4[k * 8 + 2 * l + 1];
            o[0] += hk * wa.x; o[1] += hk * wa.y; o[2] += hk * wa.z; o[3] += hk * wa.w;
            o[4] += hk * wb.x; o[5] += hk * wb.y; o[6] += hk * wb.z; o[7] += hk * wb.w;
        }
    }
    __half2 r0 = __floats2half2_rn(di * o[0], di * o[1]);
    __half2 r1 = __floats2half2_rn(di * o[2], di * o[3]);
    __half2 r2 = __floats2half2_rn(di * o[4], di * o[5]);
    __half2 r3 = __floats2half2_rn(di * o[6], di * o[7]);
    float4 st;
    st.x = *reinterpret_cast<float*>(&r0);
    st.y = *reinterpret_cast<float*>(&r1);
    st.z = *reinterpret_cast<float*>(&r2);
    st.w = *reinterpret_cast<float*>(&r3);
    ((float4*)p2)[node * 4 + l] = st;
}

// ---------------- gather layer 2 + mu/logvar epilogue (4 lanes/node) ----------
__global__ __launch_bounds__(256) void k_gfin(const int* __restrict__ deg,
                                              const int* __restrict__ srcByDst,
                                              const __half* __restrict__ p2,
                                              const float* __restrict__ bmu,
                                              const float* __restrict__ blv,
                                              float* __restrict__ out) {
    __shared__ float sB[32];
    int t = threadIdx.x;
    if (t < 32) sB[t] = (t < 16) ? bmu[t] : blv[t - 16];
    __syncthreads();
    int l = t & 3;
    int node = blockIdx.x * 64 + (t >> 2);
    if (node >= N_NODES) return;
    const float4* P = (const float4*)p2;
    int dgw = deg[node];
    int dg = (dgw < DCAP) ? dgw : DCAP;
    int beg = node * DCAP;
    float di = rsqrtf((float)(dgw + 1));
    float acc[8] = {0.f, 0.f, 0.f, 0.f, 0.f, 0.f, 0.f, 0.f};
    gatherRow4(srcByDst, P, beg, beg + dg, l, acc);
    float4 ps = P[node * 4 + l];
    float v[8];
#pragma unroll
    for (int c = 0; c < 4; ++c) {
        float2 f = __half22float2(h2of(ps, c));
        v[2 * c]     = di * (acc[2 * c]     + f.x) + sB[8 * l + 2 * c];
        v[2 * c + 1] = di * (acc[2 * c + 1] + f.y) + sB[8 * l + 2 * c + 1];
    }
    float4 o0 = make_float4(v[0], v[1], v[2], v[3]);
    float4 o1 = make_float4(v[4], v[5], v[6], v[7]);
    float4* dst4 = (l < 2) ? (float4*)out
                           : (float4*)(out + (size_t)N_NODES * 16);
    int b4 = node * 4 + (l & 1) * 2;
    dst4[b4]     = o0;
    dst4[b4 + 1] = o1;
}

extern "C" void kernel_launch(void* const* d_in, const int* in_sizes, int n_in,
                              void* d_out, int out_size, void* d_ws, size_t ws_size,
                              hipStream_t stream) {
    const float* x   = (const float*)d_in[0];
    const int*   ei  = (const int*)d_in[1];
    const float* W1  = (const float*)d_in[2];
    const float* b1  = (const float*)d_in[3];
    const float* Wmu = (const float*)d_in[4];
    const float* bmu = (const float*)d_in[5];
    const float* Wlv = (const float*)d_in[6];
    const float* blv = (const float*)d_in[7];
    float* out = (float*)d_out;

    const int* src = ei;            // edge_index[0]
    const int* dst = ei + N_EDGES;  // edge_index[1]

    // workspace (4B units), 256B-aligned big buffers for float4 access:
    //  deg[N+1]  (COUNTS, zeroed by memset below; doubles as rank cursor)
    //  | srcByDst[N*64]  (implicit CSR, fixed 64 slots/node)
    //  | p1[(N+1)*32 halves] | p2[(N+1)*32 halves]
    size_t off = 0;
    int* deg = (int*)d_ws;                              off += N_NODES + 1;
    off = (off + 63) & ~(size_t)63;                     // 256B align
    int* srcByDst = (int*)d_ws + off;                   off += (size_t)N_NODES * DCAP;
    off = (off + 63) & ~(size_t)63;
    __half* p1h = (__half*)((int*)d_ws + off);          off += (size_t)(N_NODES + 1) * 16;
    off = (off + 63) & ~(size_t)63;
    __half* p2h = (__half*)((int*)d_ws + off);

    hipMemsetAsync(d_ws, 0, (size_t)(N_NODES + 1) * sizeof(int), stream);
    k_scat<<<8 * SCAT_BPC, 512, 0, stream>>>(src, dst, deg, srcByDst);
    k_p1  <<<P1_BLOCKS, 512, 0, stream>>>(deg, x, W1, p1h);
    k_gx2 <<<NBF_G, 256, 0, stream>>>(deg, srcByDst, p1h, b1, Wmu, Wlv, p2h);
    k_gfin<<<NBF_G, 256, 0, stream>>>(deg, srcByDst, p2h, bmu, blv, out);
}